// Round 8
// baseline (191.251 us; speedup 1.0000x reference)
//
#include <hip/hip_runtime.h>

// HolographicConv: out = Re(ifft2(fft2(x) * W)), B == C_out == 16 -> pure
// elementwise complex multiply in frequency space per (b,c) image slice.
// 256 images of 256x256 complex64.  Intermediate TRANSPOSED: wsT[v*256 + k].
//
// R8 = R7 (16x16 four-step FFT-256, one LDS transpose per 1-D FFT) with the
// occupancy attribute pinned BOTH ways: amdgpu_waves_per_eu(4,4).
// R7 showed __launch_bounds__(256,4) only sets the MIN waves/EU; the
// allocator squeezed to the 8-waves/EU boundary (VGPR=64) and spilled
// (~100MB scratch traffic: FETCH 134->168MB, WRITE 134->201MB). Pinning
// max=4 gives the allocator the full 128-VGPR budget -> no spill.
//
// Layouts (derived):
//   fwd:  in lane=n1,reg=n2 -> F16(reg) -> tw w256^(m*r) -> T -> F16 ->
//         out lane=k_lo, reg=k_hi   (element k = m + 16r)
//   inv:  in lane=l_lo,reg=l_hi -> F16 -> T -> tw w256^(+m*r) -> F16 ->
//         out lane=n_lo, reg=n_hi  (element n = m + 16r)
//   K2: fwd output layout == inverse input layout == W-coalesced. 2 T total.

#define PI_F 3.14159265358979323846f

#define OCC_ATTR __attribute__((amdgpu_flat_work_group_size(256, 256), \
                                amdgpu_waves_per_eu(4, 4)))

__device__ __forceinline__ float2 cadd(float2 a, float2 b){ return make_float2(a.x+b.x, a.y+b.y); }
__device__ __forceinline__ float2 csub(float2 a, float2 b){ return make_float2(a.x-b.x, a.y-b.y); }
__device__ __forceinline__ float2 cmul2(float2 a, float2 b){
  return make_float2(a.x*b.x - a.y*b.y, a.x*b.y + a.y*b.x);
}

template<int DIR>
__device__ __forceinline__ float2 tw16c(float cx, float cy){   // conj for DIR<0
  return make_float2(cx, (DIR > 0) ? cy : -cy);
}

template<int DIR>   // +1: e^{-i} forward, -1: e^{+i} inverse (unnormalized)
__device__ __forceinline__ void bfly1(float2& a, float2& b, float2& c, float2& d)
{
  float2 apc = cadd(a,c), amc = csub(a,c);
  float2 bpd = cadd(b,d), bmd = csub(b,d);
  float2 jb = (DIR > 0) ? make_float2(-bmd.y, bmd.x)    //  i*(b-d)
                        : make_float2( bmd.y,-bmd.x);   // -i*(b-d)
  a = cadd(apc, bpd);
  b = csub(amc, jb);
  c = csub(apc, bpd);
  d = cadd(amc, jb);
}

template<int DIR>
__device__ __forceinline__ void bfly1t(float2& a, float2& b, float2& c, float2& d,
                                       float2 w1, float2 w2, float2 w3)
{
  bfly1<DIR>(a, b, c, d);
  b = cmul2(b, w1); c = cmul2(c, w2); d = cmul2(d, w3);
}

// In-register FFT-16 over the array index (natural order in and out).
template<int DIR>
__device__ __forceinline__ void fft16(float2 (&x)[16])
{
  const float C1 = 0.92387953251128675613f, S1 = 0.38268343236508977173f;
  const float C2 = 0.70710678118654752440f;
  const float2 W1 = tw16c<DIR>( C1, -S1), W2 = tw16c<DIR>( C2, -C2);
  const float2 W3 = tw16c<DIR>( S1, -C1), W4 = tw16c<DIR>(0.f, -1.f);
  const float2 W6 = tw16c<DIR>(-C2, -C2), W9 = tw16c<DIR>(-C1,  S1);
  bfly1 <DIR>(x[0], x[4], x[8],  x[12]);
  bfly1t<DIR>(x[1], x[5], x[9],  x[13], W1, W2, W3);
  bfly1t<DIR>(x[2], x[6], x[10], x[14], W2, W4, W6);
  bfly1t<DIR>(x[3], x[7], x[11], x[15], W3, W6, W9);
  float2 y[16];
  #pragma unroll
  for (int p = 0; p < 4; ++p) {
    float2 a = x[4*p+0], b = x[4*p+1], c = x[4*p+2], d = x[4*p+3];
    bfly1<DIR>(a, b, c, d);
    y[p+0] = a; y[p+4] = b; y[p+8] = c; y[p+12] = d;
  }
  #pragma unroll
  for (int i = 0; i < 16; ++i) x[i] = y[i];
}

// x[r] *= w256^(DIR_sign * m * r): one fast sincos + iterative power chain.
template<int DIR>
__device__ __forceinline__ void twiddle256(float2 (&x)[16], int m)
{
  float sv, cv;
  __sincosf(((DIR > 0) ? -2.0f : 2.0f) * PI_F * (float)m * (1.0f/256.0f), &sv, &cv);
  const float2 w = make_float2(cv, sv);
  float2 p = w;
  x[1] = cmul2(x[1], p);
  #pragma unroll
  for (int r = 2; r < 16; ++r) { p = cmul2(p, w); x[r] = cmul2(x[r], p); }
}

// 16x16 transpose within a 16-lane group. M = this column's matrix
// (16 rows x pad 19 f2). Write M[reg][lane], read M[lane][reg].
__device__ __forceinline__ void transpose16(float2 (&x)[16], float2* M, int m)
{
  __builtin_amdgcn_wave_barrier();
  #pragma unroll
  for (int r = 0; r < 16; ++r) M[r*19 + m] = x[r];
  __builtin_amdgcn_wave_barrier();               // in-order LDS per wave
  #pragma unroll
  for (int r = 0; r < 16; ++r) x[r] = M[m*19 + r];
  __builtin_amdgcn_wave_barrier();
}

// ---------------- K1: FFT over u, write wsT[v][k] --------------------------
__global__ OCC_ATTR void k_colfft(const float* __restrict__ xr,
                                  const float* __restrict__ xi,
                                  float2* __restrict__ wsT)
{
  __shared__ float2 pool[4864];   // tile f2[256][18] (4608) | mats 16x304, aliased
  const int tid  = threadIdx.x;
  const int imgl = blockIdx.x >> 4;
  const int v0   = (blockIdx.x & 15) * 16;
  const float* xrb = xr + (size_t)imgl * 65536 + v0;
  const float* xib = xi + (size_t)imgl * 65536 + v0;
  float2*      wsb = wsT + (size_t)imgl * 65536;
  const int q = tid & 3, h0 = tid >> 2;
  #pragma unroll
  for (int t = 0; t < 4; ++t) {
    const int u = h0 + 64*t;
    float4 r4 = *(const float4*)(xrb + u*256 + 4*q);
    float4 i4 = *(const float4*)(xib + u*256 + 4*q);
    float4* row = (float4*)(pool + u*18);        // 144B rows: 16B-aligned
    row[2*q]   = make_float4(r4.x, i4.x, r4.y, i4.y);
    row[2*q+1] = make_float4(r4.z, i4.z, r4.w, i4.w);
  }
  __syncthreads();
  const int lane = tid & 63, m = lane & 15;
  const int col  = (tid >> 6)*4 + (lane >> 4);   // column this lane serves
  float2 x[16];
  #pragma unroll
  for (int j = 0; j < 16; ++j) x[j] = pool[(m + 16*j)*18 + col];
  __syncthreads();                               // tile dead; mats overwrite
  float2* M = pool + col*304;
  fft16<1>(x);
  twiddle256<1>(x, m);
  transpose16(x, M, m);
  fft16<1>(x);
  float2* o = wsb + (size_t)(v0 + col) * 256;    // row v contiguous over k
  #pragma unroll
  for (int r = 0; r < 16; ++r) o[m + 16*r] = x[r];
}

// ---------------- K2: FFT over v, * W, IFFT over v (in-place on wsT) -------
__global__ OCC_ATTR void k_rowpass(float2* __restrict__ wsT,
                                   const float* __restrict__ wr,
                                   const float* __restrict__ wi,
                                   int img0)
{
  __shared__ float2 pool[4864];   // tile f2[256][18] | mats 16x304, aliased
  const int tid  = threadIdx.x;
  const int imgl = blockIdx.x >> 4;
  const int k0   = (blockIdx.x & 15) * 16;
  float2* wsb = wsT + (size_t)imgl * 65536 + k0;
  const int c8 = tid & 7, h0 = tid >> 3;
  #pragma unroll
  for (int t = 0; t < 8; ++t) {
    const int v = h0 + 32*t;
    ((float4*)(pool + v*18))[c8] = *(const float4*)(wsb + v*256 + 2*c8);
  }
  __syncthreads();
  const int lane = tid & 63, m = lane & 15;
  const int col  = (tid >> 6)*4 + (lane >> 4);
  float2 x[16];
  #pragma unroll
  for (int j = 0; j < 16; ++j) x[j] = pool[(m + 16*j)*18 + col];
  __syncthreads();                               // tile dead; mats overwrite
  // W for this column, layout-matched to fwd output (l = m + 16r):
  // contiguous per group -> coalesced. Issued early; hides under fwd FFT.
  const size_t wcb = (size_t)(img0 + imgl) * 65536 + (size_t)(k0 + col) * 256 + m;
  const float* wrc = wr + wcb;
  const float* wic = wi + wcb;
  float2 wv[16];
  #pragma unroll
  for (int r = 0; r < 16; ++r) wv[r] = make_float2(wrc[16*r], wic[16*r]);
  float2* M = pool + col*304;
  fft16<1>(x);
  twiddle256<1>(x, m);
  transpose16(x, M, m);
  fft16<1>(x);                                   // lane=k_lo, reg=k_hi
  #pragma unroll
  for (int r = 0; r < 16; ++r) x[r] = cmul2(x[r], wv[r]);
  fft16<-1>(x);                                  // inverse: same layout in
  transpose16(x, M, m);
  twiddle256<-1>(x, m);
  fft16<-1>(x);                                  // lane=n_lo, reg=n_hi
  __syncthreads();                               // mats dead; tile writeback
  #pragma unroll
  for (int r = 0; r < 16; ++r) pool[(m + 16*r)*18 + col] = x[r];
  __syncthreads();
  #pragma unroll
  for (int t = 0; t < 8; ++t) {
    const int v = h0 + 32*t;
    *(float4*)(wsb + v*256 + 2*c8) = ((float4*)(pool + v*18))[c8];
  }
}

// ---------------- K3: IFFT over k, write Re/65536 --------------------------
__global__ OCC_ATTR void k_rowifft(const float2* __restrict__ wsT,
                                   float* __restrict__ out)
{
  __shared__ float2 pool[4864];   // mats 16x304 | out-tile f32[256][20], aliased
  const int tid  = threadIdx.x;
  const int imgl = blockIdx.x >> 4;
  const int v0   = (blockIdx.x & 15) * 16;
  const float2* wsb = wsT + (size_t)imgl * 65536;
  float*        ob  = out + (size_t)imgl * 65536 + v0;
  const int lane = tid & 63, m = lane & 15;
  const int col  = (tid >> 6)*4 + (lane >> 4);
  const float2* src = wsb + (size_t)(v0 + col) * 256;  // row v: contiguous k
  float2 x[16];
  #pragma unroll
  for (int r = 0; r < 16; ++r) x[r] = src[m + 16*r];   // coalesced direct
  float2* M = pool + col*304;
  fft16<-1>(x);
  transpose16(x, M, m);
  twiddle256<-1>(x, m);
  fft16<-1>(x);                                  // lane=n_lo(u), reg=n_hi
  __syncthreads();                               // mats dead; out-tile
  float* ot = (float*)pool;                      // [256][20] f32
  const float sc = 1.0f / 65536.0f;
  #pragma unroll
  for (int r = 0; r < 16; ++r) ot[(m + 16*r)*20 + col] = x[r].x * sc;
  __syncthreads();
  const int q = tid & 3, h0 = tid >> 2;
  #pragma unroll
  for (int t = 0; t < 4; ++t) {
    const int u = h0 + 64*t;
    *(float4*)(ob + u*256 + 4*q) = *(const float4*)(ot + u*20 + 4*q);
  }
}

extern "C" void kernel_launch(void* const* d_in, const int* in_sizes, int n_in,
                              void* d_out, int out_size, void* d_ws, size_t ws_size,
                              hipStream_t stream)
{
  const float* xr = (const float*)d_in[0];
  const float* xi = (const float*)d_in[1];
  const float* wr = (const float*)d_in[2];
  const float* wi = (const float*)d_in[3];
  float* out = (float*)d_out;

  const int IMG = 256;                                    // B * C_IN
  const size_t per_img = (size_t)65536 * sizeof(float2);  // 512 KiB
  int ipc = (int)(ws_size / per_img);                     // images per chunk
  if (ipc < 1)   ipc = 1;
  if (ipc > IMG) ipc = IMG;
  float2* wsp = (float2*)d_ws;

  for (int img0 = 0; img0 < IMG; img0 += ipc) {
    const int n = (IMG - img0 < ipc) ? (IMG - img0) : ipc;
    k_colfft <<<dim3(n*16), dim3(256), 0, stream>>>(xr + (size_t)img0*65536,
                                                    xi + (size_t)img0*65536, wsp);
    k_rowpass<<<dim3(n*16), dim3(256), 0, stream>>>(wsp, wr, wi, img0);
    k_rowifft<<<dim3(n*16), dim3(256), 0, stream>>>(wsp, out + (size_t)img0*65536);
  }
}